// Round 15
// baseline (446.529 us; speedup 1.0000x reference)
//
#include <hip/hip_runtime.h>
#include <hip/hip_bf16.h>
#include <stdint.h>

// Problem constants
// N=2, T=65536, DIM=256, HEADS=8, DH=32, NB=256 windows of TB=256 tokens, DFF=512
#define NTOK   131072      // N*T rows
#define NWIN   512         // N * NB

typedef __attribute__((ext_vector_type(4))) float f32x4;
typedef __attribute__((ext_vector_type(8))) short s16x8;
typedef __attribute__((ext_vector_type(4))) short s16x4;
typedef __attribute__((ext_vector_type(8))) unsigned short u16x8;

#define MFMA16(A,B,C) __builtin_amdgcn_mfma_f32_16x16x32_bf16(A,B,C,0,0,0)

__device__ __forceinline__ unsigned short f2bf(float f) {
  union { float f; unsigned u; } v; v.f = f;
  return (unsigned short)((v.u + 0x7fffu + ((v.u >> 16) & 1u)) >> 16);
}
__device__ __forceinline__ float bf2f(unsigned short u) {
  union { unsigned u; float f; } v; v.u = ((unsigned)u) << 16;
  return v.f;
}

__device__ __forceinline__ float redsum16(float v) {
  v += __shfl_xor(v, 1, 64);
  v += __shfl_xor(v, 2, 64);
  v += __shfl_xor(v, 4, 64);
  v += __shfl_xor(v, 8, 64);
  return v;
}

// ---------------------------------------------------------------------------
// K0: x fp32 -> xb bf16. Pure bandwidth.
// ---------------------------------------------------------------------------
__global__ __launch_bounds__(256) void k_cast(const float* __restrict__ x,
                                              unsigned short* __restrict__ xb) {
  const long total = (long)NTOK * 256 / 8;
  long stride = (long)gridDim.x * 256;
  for (long c = blockIdx.x * 256 + threadIdx.x; c < total; c += stride) {
    const f32x4* p = (const f32x4*)(x + c * 8);
    f32x4 v0 = p[0], v1 = p[1];
    u16x8 o;
    o[0] = f2bf(v0[0]); o[1] = f2bf(v0[1]); o[2] = f2bf(v0[2]); o[3] = f2bf(v0[3]);
    o[4] = f2bf(v1[0]); o[5] = f2bf(v1[1]); o[6] = f2bf(v1[2]); o[7] = f2bf(v1[3]);
    *(u16x8*)(xb + c * 8) = o;
  }
}

// ---------------------------------------------------------------------------
// Weight repack fp32->bf16, [outcol][k].
// Wqkv col regroup: src col = d*24 + s*8 + h -> dst col = h*96 + s*32 + d.
// W2 k-PERMUTED within each 64-block (round-8/9 proven): kp -> korig =
// (kp&~63) | ((kp&3)<<4) | ((kp>>2)&15)  — matches k_ff's P layout.
// ---------------------------------------------------------------------------
__global__ void k_prep(const float* __restrict__ Wqkv, const float* __restrict__ W0,
                       const float* __restrict__ W1,  const float* __restrict__ W2,
                       unsigned short* __restrict__ wqkv_t, unsigned short* __restrict__ w0t,
                       unsigned short* __restrict__ w1t,   unsigned short* __restrict__ w2tr) {
  int tid = blockIdx.x * 256 + threadIdx.x;
  int nthr = gridDim.x * 256;
  for (int i = tid; i < 768 * 256; i += nthr) {
    int col = i >> 8, k = i & 255;
    int h = col / 96, rem = col % 96;
    int s = rem >> 5, d = rem & 31;
    wqkv_t[i] = f2bf(Wqkv[k * 768 + d * 24 + s * 8 + h]);
  }
  for (int i = tid; i < 256 * 256; i += nthr) {
    int col = i >> 8, k = i & 255;
    w0t[i] = f2bf(W0[k * 256 + col]);
  }
  for (int i = tid; i < 512 * 256; i += nthr) {
    int col = i >> 8, k = i & 255;
    w1t[i] = f2bf(W1[k * 512 + col]);
  }
  for (int i = tid; i < 256 * 512; i += nthr) {
    int col = i >> 9, kp = i & 511;
    int korig = (kp & 0x1C0) | (((kp & 3) << 4) | ((kp >> 2) & 15));
    w2tr[i] = f2bf(W2[korig * 256 + col]);
  }
}

// ---------------------------------------------------------------------------
// Shared GEMM core (2-phase prefetch): C[256][256] = A[256][K] * Bt[col][k].
// ---------------------------------------------------------------------------
__device__ __forceinline__ void gemm_block(
    const unsigned short* __restrict__ A, int a_stride,
    const unsigned short* __restrict__ Bt, int bcol0, int b_stride, int K,
    unsigned short* As, unsigned short* Bs, f32x4 acc[2][16])
{
  const int tid = threadIdx.x;
  const int wid = tid >> 6, lane = tid & 63, lr = lane & 15, lg = lane >> 4;
  const f32x4 Z = {0.f, 0.f, 0.f, 0.f};
#pragma unroll
  for (int m = 0; m < 2; ++m)
#pragma unroll
    for (int n = 0; n < 16; ++n) acc[m][n] = Z;

  u16x8 pa[4], pb[4];
#pragma unroll
  for (int j = 0; j < 4; ++j) {
    int e = (tid + j * 512) << 3; int row = e >> 6, kk = e & 63;
    pa[j] = *(const u16x8*)(A + (long)row * a_stride + kk);
    pb[j] = *(const u16x8*)(Bt + (long)(bcol0 + row) * b_stride + kk);
  }

  for (int k0 = 0; k0 < K; k0 += 64) {
#pragma unroll
    for (int j = 0; j < 4; ++j) {
      int e = (tid + j * 512) << 3; int row = e >> 6, kk = e & 63;
      int sw = kk ^ ((row & 7) << 3);
      *(u16x8*)&As[row * 64 + sw] = pa[j];
      *(u16x8*)&Bs[row * 64 + sw] = pb[j];
    }
    __syncthreads();
    if (k0 + 64 < K) {
#pragma unroll
      for (int j = 0; j < 4; ++j) {
        int e = (tid + j * 512) << 3; int row = e >> 6, kk = e & 63;
        pa[j] = *(const u16x8*)(A + (long)row * a_stride + k0 + 64 + kk);
        pb[j] = *(const u16x8*)(Bt + (long)(bcol0 + row) * b_stride + k0 + 64 + kk);
      }
    }
#pragma unroll
    for (int ks = 0; ks < 2; ++ks) {
      int kb = ks * 32 + lg * 8;
      s16x8 a[2];
#pragma unroll
      for (int m = 0; m < 2; ++m) {
        int row = wid * 32 + m * 16 + lr;
        a[m] = *(const s16x8*)&As[row * 64 + (kb ^ ((row & 7) << 3))];
      }
#pragma unroll
      for (int n = 0; n < 16; ++n) {
        int col = n * 16 + lr;
        s16x8 b = *(const s16x8*)&Bs[col * 64 + (kb ^ ((col & 7) << 3))];
        acc[0][n] = MFMA16(a[0], b, acc[0][n]);
        acc[1][n] = MFMA16(a[1], b, acc[1][n]);
      }
    }
    __syncthreads();
  }
}

// ---------------------------------------------------------------------------
// K2: qkv = xb @ Wqkv  (per window, N split in 3 x 256 cols), XCD swizzle.
// Output layout: qkv[w][tok][768] row-major, cols regrouped h*96+s*32+d.
// (round-9 proven, verbatim)
// ---------------------------------------------------------------------------
__global__ __launch_bounds__(512) void k_qkv(const unsigned short* __restrict__ xb,
    const unsigned short* __restrict__ wqkv_t, unsigned short* __restrict__ qkv) {
  __shared__ __align__(16) unsigned short Ls[256 * 128];
  int orig = blockIdx.x;            // 1536 = 8 * 192
  int bid = (orig & 7) * 192 + (orig >> 3);
  int ns = bid % 3, w = bid / 3;
  f32x4 acc[2][16];
  gemm_block(xb + (long)w * 65536, 256, wqkv_t, ns * 256, 256, 256,
             Ls, Ls + 256 * 64, acc);

  const int tid = threadIdx.x, wid = tid >> 6, lane = tid & 63, lr = lane & 15, lg = lane >> 4;
  long wrow0 = (long)w * 256;
#pragma unroll
  for (int pass = 0; pass < 2; ++pass) {
    __syncthreads();
    if ((wid >> 2) == pass) {
      unsigned short* R = Ls + (wid & 3) * 8192;           // [32][256]
#pragma unroll
      for (int m = 0; m < 2; ++m)
#pragma unroll
        for (int n = 0; n < 16; ++n)
#pragma unroll
          for (int r = 0; r < 4; ++r) {
            int trow = m * 16 + lg * 4 + r;
            int col = n * 16 + lr;
            R[trow * 256 + (col ^ ((trow & 7) << 3))] = f2bf(acc[m][n][r]);
          }
    }
    __syncthreads();
    if ((wid >> 2) == pass) {
      unsigned short* R = Ls + (wid & 3) * 8192;
#pragma unroll
      for (int c = 0; c < 16; ++c) {
        int flat = c * 512 + lane * 8;
        int trow = flat >> 8, col0 = flat & 255;
        u16x8 v = *(const u16x8*)&R[trow * 256 + (col0 ^ ((trow & 7) << 3))];
        int tok = wid * 32 + trow;
        *(u16x8*)(qkv + (wrow0 + tok) * 768 + ns * 256 + col0) = v;
      }
    }
  }
}

// ---------------------------------------------------------------------------
// K3: attention per (n, window, head), quartered streaming softmax (no max).
// XCD-grouped swizzle.  Round-9 proven, verbatim.
// ---------------------------------------------------------------------------
__global__ __launch_bounds__(512) void k_attn(const unsigned short* __restrict__ qkv,
                                              unsigned short* __restrict__ attn) {
  __shared__ __align__(16) unsigned short vt[32 * 256];
  __shared__ __align__(16) unsigned short Pw[8 * 32 * 64];
  const int tid = threadIdx.x, wid = tid >> 6, lane = tid & 63, lr = lane & 15, lg = lane >> 4;
  const int orig = blockIdx.x;
  const int c = orig & 7, xx = orig >> 3;
  const int w = c * 64 + (xx >> 3), h = xx & 7;
  const unsigned short* qm = qkv + (long)w * 196608 + h * 96;
  const unsigned short* km = qm + 32;
  const unsigned short* vm = qm + 64;

  // stage V transposed + j-permuted: vt[d][p(tok) ^ ((d&7)<<3)]
  for (int i = tid; i < 1024; i += 512) {
    int e = i << 3; int tok = e >> 5, d0 = e & 31;
    int p = (tok & 0xC0) | ((tok & 15) << 2) | ((tok >> 4) & 3);
    u16x8 vv = *(const u16x8*)(vm + (long)tok * 768 + d0);
#pragma unroll
    for (int j = 0; j < 8; ++j) {
      int d = d0 + j;
      vt[d * 256 + (p ^ ((d & 7) << 3))] = vv[j];
    }
  }

  s16x8 a[2];
#pragma unroll
  for (int m = 0; m < 2; ++m) {
    int row = wid * 32 + m * 16 + lr;
    a[m] = *(const s16x8*)(qm + (long)row * 768 + lg * 8);
  }

  const f32x4 Z = {0.f, 0.f, 0.f, 0.f};
  f32x4 o[2][2];
  o[0][0] = Z; o[0][1] = Z; o[1][0] = Z; o[1][1] = Z;
  float fsum[2][4];
#pragma unroll
  for (int m = 0; m < 2; ++m)
#pragma unroll
    for (int r = 0; r < 4; ++r) fsum[m][r] = 0.f;

  unsigned short* P = &Pw[wid * 2048];

  __syncthreads();   // vt staged

  const float SC = 0.17677669529663687f * 1.4426950408889634f;

#pragma unroll
  for (int qd = 0; qd < 4; ++qd) {
    f32x4 s[2][4];
#pragma unroll
    for (int m = 0; m < 2; ++m)
#pragma unroll
      for (int n4 = 0; n4 < 4; ++n4) s[m][n4] = Z;
#pragma unroll
    for (int n4 = 0; n4 < 4; ++n4) {
      int col = (qd * 4 + n4) * 16 + lr;
      s16x8 bfr = *(const s16x8*)(km + (long)col * 768 + lg * 8);
      s[0][n4] = MFMA16(a[0], bfr, s[0][n4]);
      s[1][n4] = MFMA16(a[1], bfr, s[1][n4]);
    }
#pragma unroll
    for (int m = 0; m < 2; ++m)
#pragma unroll
      for (int r = 0; r < 4; ++r) {
        float p0, p1, p2, p3;
        asm("v_exp_f32 %0, %1" : "=v"(p0) : "v"(s[m][0][r] * SC));
        asm("v_exp_f32 %0, %1" : "=v"(p1) : "v"(s[m][1][r] * SC));
        asm("v_exp_f32 %0, %1" : "=v"(p2) : "v"(s[m][2][r] * SC));
        asm("v_exp_f32 %0, %1" : "=v"(p3) : "v"(s[m][3][r] * SC));
        fsum[m][r] += (p0 + p1) + (p2 + p3);
        unsigned lo, hi;
        asm("v_cvt_pk_bf16_f32 %0, %1, %2" : "=v"(lo) : "v"(p0), "v"(p1));
        asm("v_cvt_pk_bf16_f32 %0, %1, %2" : "=v"(hi) : "v"(p2), "v"(p3));
        int prow = m * 16 + lg * 4 + r;
        uint2 val; val.x = lo; val.y = hi;
        *(uint2*)&P[prow * 64 + ((lr * 4) ^ ((prow & 7) << 3))] = val;
      }
#pragma unroll
    for (int ks = 0; ks < 2; ++ks) {
      s16x8 pa[2];
#pragma unroll
      for (int m = 0; m < 2; ++m) {
        int prow = m * 16 + lr;
        pa[m] = *(const s16x8*)&P[prow * 64 + ((ks * 32 + lg * 8) ^ ((prow & 7) << 3))];
      }
#pragma unroll
      for (int nd = 0; nd < 2; ++nd) {
        int d = nd * 16 + lr;
        int jb = qd * 64 + ks * 32 + lg * 8;
        s16x8 vb = *(const s16x8*)&vt[d * 256 + (jb ^ ((d & 7) << 3))];
        o[0][nd] = MFMA16(pa[0], vb, o[0][nd]);
        o[1][nd] = MFMA16(pa[1], vb, o[1][nd]);
      }
    }
  }

  long obase = ((long)w * 256) * 256 + h * 32;
#pragma unroll
  for (int m = 0; m < 2; ++m)
#pragma unroll
    for (int r = 0; r < 4; ++r) {
      float rinv = 1.f / redsum16(fsum[m][r]);
      int tok = wid * 32 + m * 16 + lg * 4 + r;
#pragma unroll
      for (int nd = 0; nd < 2; ++nd) {
        int d = nd * 16 + lr;
        attn[obase + (long)tok * 256 + d] = f2bf(o[m][nd][r] * rinv);
      }
    }
}

// ---------------------------------------------------------------------------
// K4: out = attn @ W0 + x ; y = LN1(out)  (y bf16 to global)  [proven]
// ---------------------------------------------------------------------------
__global__ __launch_bounds__(512) void k_proj_ln1(
    const unsigned short* __restrict__ attn, const unsigned short* __restrict__ xb,
    const unsigned short* __restrict__ w0t, const float* __restrict__ g1,
    const float* __restrict__ be1, unsigned short* __restrict__ y) {
  __shared__ __align__(16) unsigned short As[256 * 64];
  __shared__ __align__(16) unsigned short Bs[256 * 64];
  int w = blockIdx.x;
  long row0 = (long)w * 256;
  f32x4 acc[2][16];
  gemm_block(attn + row0 * 256, 256, w0t, 0, 256, 256, As, Bs, acc);

  const int tid = threadIdx.x, wid = tid >> 6, lane = tid & 63, lr = lane & 15, lg = lane >> 4;
#pragma unroll
  for (int m = 0; m < 2; ++m)
#pragma unroll
    for (int r = 0; r < 4; ++r) {
      int row = wid * 32 + m * 16 + lg * 4 + r;
      long grow = row0 + row;
      float v[16]; float sum = 0.f;
#pragma unroll
      for (int n = 0; n < 16; ++n) {
        int col = n * 16 + lr;
        v[n] = acc[m][n][r] + bf2f(xb[grow * 256 + col]);
        sum += v[n];
      }
      sum = redsum16(sum);
      float mu = sum * (1.f / 256.f);
      float vs = 0.f;
#pragma unroll
      for (int n = 0; n < 16; ++n) { float dd = v[n] - mu; vs += dd * dd; }
      vs = redsum16(vs);
      float rstd = rsqrtf(vs * (1.f / 256.f) + 1e-5f);
#pragma unroll
      for (int n = 0; n < 16; ++n) {
        int col = n * 16 + lr;
        y[grow * 256 + col] = f2bf((v[n] - mu) * rstd * g1[col] + be1[col]);
      }
    }
}

// ---------------------------------------------------------------------------
// K5 (fused ff, v6 = v5 + double-buffered weights + wave-local P):
// Occupancy is register-bound at 1 block/CU (round 13), so LDS is free:
// w1s/w2s are double-buffered (144KB total) and the slab loop runs with
// ONE barrier per slab instead of three.  The per-wave P tile needs no
// barrier at all — wave DS ops are in-order, same idiom k_attn has proven
// across 5 passing rounds (uint2 write -> s16x8 read, same wave).
// Hazard check for the single barrier: buf[(s+1)&1] written at slab s+1
// was last read at slab s-1, and those reads complete before barrier(s)
// (each wave signals barrier(s) only after finishing slab s-1's compute).
// Per slab: write-stage buf[s&1] -> barrier -> prefetch s+1 -> GEMM2a
// (yfrag x w1s[b]) -> relu+b1 -> P (wave-local) -> GEMM2b (P x w2s[b]).
// ---------------------------------------------------------------------------
__global__ __launch_bounds__(512) void k_ff(
    const unsigned short* __restrict__ y, const unsigned short* __restrict__ w1t,
    const float* __restrict__ b1, const unsigned short* __restrict__ w2tr,
    const float* __restrict__ b2, const float* __restrict__ g2,
    const float* __restrict__ be2, float* __restrict__ out) {
  __shared__ __align__(16) unsigned short w1s[2][64 * 256];  // 2 x 32 KB
  __shared__ __align__(16) unsigned short w2s[2][256 * 64];  // 2 x 32 KB
  __shared__ __align__(16) unsigned short ps[8 * 16 * 64];   // 16 KB
  const int tid = threadIdx.x, wid = tid >> 6, lane = tid & 63, lr = lane & 15, lg = lane >> 4;
  const long row0 = (long)blockIdx.x * 128;
  const f32x4 Z = {0.f, 0.f, 0.f, 0.f};

  const unsigned short* yrow = y + (row0 + wid * 16 + lr) * 256;

  // y A-fragments in registers for the whole kernel (read global ONCE)
  s16x8 yfrag[8];
#pragma unroll
  for (int ks = 0; ks < 8; ++ks)
    yfrag[ks] = *(const s16x8*)(yrow + ks * 32 + lg * 8);

  f32x4 acc2[16];
#pragma unroll
  for (int n = 0; n < 16; ++n) acc2[n] = Z;
  unsigned short* P = ps + wid * 1024;   // [16][64] per wave

  // staging: 16384 elems each, 4 x u16x8 per thread
  u16x8 pw1[4], pw2[4];
#pragma unroll
  for (int j = 0; j < 4; ++j) {
    int e = (tid + j * 512) << 3;
    int c1 = e >> 8, k1 = e & 255;          // w1: col(0..63), k(0..255)
    int c2 = e >> 6, k2 = e & 63;           // w2: col(0..255), k(0..63)
    pw1[j] = *(const u16x8*)(w1t + (long)c1 * 256 + k1);
    pw2[j] = *(const u16x8*)(w2tr + (long)c2 * 512 + k2);
  }

  for (int s = 0; s < 8; ++s) {
    const int b = s & 1;
#pragma unroll
    for (int j = 0; j < 4; ++j) {
      int e = (tid + j * 512) << 3;
      int c1 = e >> 8, k1 = e & 255;
      int c2 = e >> 6, k2 = e & 63;
      *(u16x8*)&w1s[b][c1 * 256 + (k1 ^ ((c1 & 7) << 3))] = pw1[j];
      *(u16x8*)&w2s[b][c2 * 64 + (k2 ^ ((c2 & 7) << 3))] = pw2[j];
    }
    __syncthreads();                       // stage visible; prior buf reads done
    if (s + 1 < 8) {
#pragma unroll
      for (int j = 0; j < 4; ++j) {
        int e = (tid + j * 512) << 3;
        int c1 = e >> 8, k1 = e & 255;
        int c2 = e >> 6, k2 = e & 63;
        pw1[j] = *(const u16x8*)(w1t + (long)((s + 1) * 64 + c1) * 256 + k1);
        pw2[j] = *(const u16x8*)(w2tr + (long)c2 * 512 + (s + 1) * 64 + k2);
      }
    }
    // GEMM2a: sacc = yfrag(16 rows) x W1s(64 cols), K=256
    f32x4 sacc[4];
#pragma unroll
    for (int n4 = 0; n4 < 4; ++n4) sacc[n4] = Z;
#pragma unroll
    for (int ks = 0; ks < 8; ++ks) {
#pragma unroll
      for (int n4 = 0; n4 < 4; ++n4) {
        int col = n4 * 16 + lr;
        s16x8 bb = *(const s16x8*)&w1s[b][col * 256 + ((ks * 32 + lg * 8) ^ ((col & 7) << 3))];
        sacc[n4] = MFMA16(yfrag[ks], bb, sacc[n4]);
      }
    }
    // relu + b1 -> P (kp = lr*4 + n4); wave-local, no barrier (k_attn idiom)
#pragma unroll
    for (int r = 0; r < 4; ++r) {
      int prow = lg * 4 + r;
      float p0 = fmaxf(sacc[0][r] + b1[s * 64 + lr], 0.f);
      float p1 = fmaxf(sacc[1][r] + b1[s * 64 + 16 + lr], 0.f);
      float p2 = fmaxf(sacc[2][r] + b1[s * 64 + 32 + lr], 0.f);
      float p3 = fmaxf(sacc[3][r] + b1[s * 64 + 48 + lr], 0.f);
      unsigned lo, hi;
      asm("v_cvt_pk_bf16_f32 %0, %1, %2" : "=v"(lo) : "v"(p0), "v"(p1));
      asm("v_cvt_pk_bf16_f32 %0, %1, %2" : "=v"(hi) : "v"(p2), "v"(p3));
      uint2 val; val.x = lo; val.y = hi;
      *(uint2*)&P[prow * 64 + ((lr * 4) ^ ((prow & 7) << 3))] = val;
    }
    // GEMM2b: acc2 += P x W2s (K=64, permuted to match P)
#pragma unroll
    for (int ks2 = 0; ks2 < 2; ++ks2) {
      s16x8 pa2 = *(const s16x8*)&P[lr * 64 + ((ks2 * 32 + lg * 8) ^ ((lr & 7) << 3))];
#pragma unroll
      for (int n = 0; n < 16; ++n) {
        int col = n * 16 + lr;
        s16x8 bb = *(const s16x8*)&w2s[b][col * 64 + ((ks2 * 32 + lg * 8) ^ ((col & 7) << 3))];
        acc2[n] = MFMA16(pa2, bb, acc2[n]);
      }
    }
  }

  // ---- +b2 + y residual, LN2 -> out
#pragma unroll
  for (int r = 0; r < 4; ++r) {
    int trow = wid * 16 + lg * 4 + r;
    long grow = row0 + trow;
    float v[16]; float sum = 0.f;
#pragma unroll
    for (int n = 0; n < 16; ++n) {
      int col = n * 16 + lr;
      v[n] = acc2[n][r] + b2[col] + bf2f(y[grow * 256 + col]);
      sum += v[n];
    }
    sum = redsum16(sum);
    float mu = sum * (1.f / 256.f);
    float vs = 0.f;
#pragma unroll
    for (int n = 0; n < 16; ++n) { float dd = v[n] - mu; vs += dd * dd; }
    vs = redsum16(vs);
    float rstd = rsqrtf(vs * (1.f / 256.f) + 1e-5f);
#pragma unroll
    for (int n = 0; n < 16; ++n) {
      int col = n * 16 + lr;
      out[grow * 256 + col] = (v[n] - mu) * rstd * g2[col] + be2[col];
    }
  }
}

// ---------------------------------------------------------------------------
// Launch. Workspace layout (bytes):
//   [0, 1MB)                weights bf16 (wqkv_t/w0t/w1t/w2tr)
//   [1MB, +67MB)            xb bf16
//   [1MB+67MB, +201MB)      qkv bf16 [w][tok][768] -> y bf16 reuses this
//   [1MB+67MB+201MB, +67MB) attn bf16
// ---------------------------------------------------------------------------
extern "C" void kernel_launch(void* const* d_in, const int* in_sizes, int n_in,
                              void* d_out, int out_size, void* d_ws, size_t ws_size,
                              hipStream_t stream) {
  (void)in_sizes; (void)n_in; (void)out_size; (void)ws_size;
  const float* x    = (const float*)d_in[0];
  const float* Wqkv = (const float*)d_in[1];
  const float* W0   = (const float*)d_in[2];
  const float* g1   = (const float*)d_in[3];
  const float* be1  = (const float*)d_in[4];
  const float* W1   = (const float*)d_in[5];
  const float* b1   = (const float*)d_in[6];
  const float* W2   = (const float*)d_in[7];
  const float* b2   = (const float*)d_in[8];
  const float* g2   = (const float*)d_in[9];
  const float* be2  = (const float*)d_in[10];
  float* out = (float*)d_out;
  char* ws = (char*)d_ws;

  unsigned short* wqkv_t = (unsigned short*)(ws);
  unsigned short* w0t    = (unsigned short*)(ws + 393216);
  unsigned short* w1t    = (unsigned short*)(ws + 524288);
  unsigned short* w2tr   = (unsigned short*)(ws + 786432);
  unsigned short* xb     = (unsigned short*)(ws + 1048576);
  char* regQ = ws + 1048576 + 67108864;
  unsigned short* qkvb   = (unsigned short*)(regQ);
  unsigned short* y      = (unsigned short*)(regQ);                  // reuse (qkv dead)
  unsigned short* attnb  = (unsigned short*)(regQ + 201326592);

  hipLaunchKernelGGL(k_cast, dim3(2048), dim3(256), 0, stream, x, xb);
  hipLaunchKernelGGL(k_prep, dim3(512), dim3(256), 0, stream,
                     Wqkv, W0, W1, W2, wqkv_t, w0t, w1t, w2tr);
  hipLaunchKernelGGL(k_qkv, dim3(NWIN * 3), dim3(512), 0, stream, xb, wqkv_t, qkvb);
  hipLaunchKernelGGL(k_attn, dim3(NWIN * 8), dim3(512), 0, stream, qkvb, attnb);
  hipLaunchKernelGGL(k_proj_ln1, dim3(NWIN), dim3(512), 0, stream,
                     attnb, xb, w0t, g1, be1, y);
  hipLaunchKernelGGL(k_ff, dim3(NTOK / 128), dim3(512), 0, stream,
                     y, w1t, b1, w2tr, b2, g2, be2, out);
}

// Round 16
// 355.845 us; speedup vs baseline: 1.2548x; 1.2548x over previous
//
#include <hip/hip_runtime.h>
#include <hip/hip_bf16.h>
#include <stdint.h>

// Problem constants
// N=2, T=65536, DIM=256, HEADS=8, DH=32, NB=256 windows of TB=256 tokens, DFF=512
#define NTOK   131072      // N*T rows
#define NWIN   512         // N * NB

typedef __attribute__((ext_vector_type(4))) float f32x4;
typedef __attribute__((ext_vector_type(8))) short s16x8;
typedef __attribute__((ext_vector_type(4))) short s16x4;
typedef __attribute__((ext_vector_type(8))) unsigned short u16x8;

#define MFMA16(A,B,C) __builtin_amdgcn_mfma_f32_16x16x32_bf16(A,B,C,0,0,0)

__device__ __forceinline__ unsigned short f2bf(float f) {
  union { float f; unsigned u; } v; v.f = f;
  return (unsigned short)((v.u + 0x7fffu + ((v.u >> 16) & 1u)) >> 16);
}
__device__ __forceinline__ float bf2f(unsigned short u) {
  union { unsigned u; float f; } v; v.u = ((unsigned)u) << 16;
  return v.f;
}

__device__ __forceinline__ float redsum16(float v) {
  v += __shfl_xor(v, 1, 64);
  v += __shfl_xor(v, 2, 64);
  v += __shfl_xor(v, 4, 64);
  v += __shfl_xor(v, 8, 64);
  return v;
}

// ---------------------------------------------------------------------------
// K0: x fp32 -> xb bf16. Pure bandwidth.
// ---------------------------------------------------------------------------
__global__ __launch_bounds__(256) void k_cast(const float* __restrict__ x,
                                              unsigned short* __restrict__ xb) {
  const long total = (long)NTOK * 256 / 8;
  long stride = (long)gridDim.x * 256;
  for (long c = blockIdx.x * 256 + threadIdx.x; c < total; c += stride) {
    const f32x4* p = (const f32x4*)(x + c * 8);
    f32x4 v0 = p[0], v1 = p[1];
    u16x8 o;
    o[0] = f2bf(v0[0]); o[1] = f2bf(v0[1]); o[2] = f2bf(v0[2]); o[3] = f2bf(v0[3]);
    o[4] = f2bf(v1[0]); o[5] = f2bf(v1[1]); o[6] = f2bf(v1[2]); o[7] = f2bf(v1[3]);
    *(u16x8*)(xb + c * 8) = o;
  }
}

// ---------------------------------------------------------------------------
// Weight repack fp32->bf16, [outcol][k].
// Wqkv col regroup: src col = d*24 + s*8 + h -> dst col = h*96 + s*32 + d.
// W2 k-PERMUTED within each 64-block (round-8/9 proven): kp -> korig =
// (kp&~63) | ((kp&3)<<4) | ((kp>>2)&15)  — matches k_ff's P layout.
// ---------------------------------------------------------------------------
__global__ void k_prep(const float* __restrict__ Wqkv, const float* __restrict__ W0,
                       const float* __restrict__ W1,  const float* __restrict__ W2,
                       unsigned short* __restrict__ wqkv_t, unsigned short* __restrict__ w0t,
                       unsigned short* __restrict__ w1t,   unsigned short* __restrict__ w2tr) {
  int tid = blockIdx.x * 256 + threadIdx.x;
  int nthr = gridDim.x * 256;
  for (int i = tid; i < 768 * 256; i += nthr) {
    int col = i >> 8, k = i & 255;
    int h = col / 96, rem = col % 96;
    int s = rem >> 5, d = rem & 31;
    wqkv_t[i] = f2bf(Wqkv[k * 768 + d * 24 + s * 8 + h]);
  }
  for (int i = tid; i < 256 * 256; i += nthr) {
    int col = i >> 8, k = i & 255;
    w0t[i] = f2bf(W0[k * 256 + col]);
  }
  for (int i = tid; i < 512 * 256; i += nthr) {
    int col = i >> 8, k = i & 255;
    w1t[i] = f2bf(W1[k * 512 + col]);
  }
  for (int i = tid; i < 256 * 512; i += nthr) {
    int col = i >> 9, kp = i & 511;
    int korig = (kp & 0x1C0) | (((kp & 3) << 4) | ((kp >> 2) & 15));
    w2tr[i] = f2bf(W2[korig * 256 + col]);
  }
}

// ---------------------------------------------------------------------------
// Shared GEMM core (2-phase prefetch): C[256][256] = A[256][K] * Bt[col][k].
// (used by k_proj_ln1)
// ---------------------------------------------------------------------------
__device__ __forceinline__ void gemm_block(
    const unsigned short* __restrict__ A, int a_stride,
    const unsigned short* __restrict__ Bt, int bcol0, int b_stride, int K,
    unsigned short* As, unsigned short* Bs, f32x4 acc[2][16])
{
  const int tid = threadIdx.x;
  const int wid = tid >> 6, lane = tid & 63, lr = lane & 15, lg = lane >> 4;
  const f32x4 Z = {0.f, 0.f, 0.f, 0.f};
#pragma unroll
  for (int m = 0; m < 2; ++m)
#pragma unroll
    for (int n = 0; n < 16; ++n) acc[m][n] = Z;

  u16x8 pa[4], pb[4];
#pragma unroll
  for (int j = 0; j < 4; ++j) {
    int e = (tid + j * 512) << 3; int row = e >> 6, kk = e & 63;
    pa[j] = *(const u16x8*)(A + (long)row * a_stride + kk);
    pb[j] = *(const u16x8*)(Bt + (long)(bcol0 + row) * b_stride + kk);
  }

  for (int k0 = 0; k0 < K; k0 += 64) {
#pragma unroll
    for (int j = 0; j < 4; ++j) {
      int e = (tid + j * 512) << 3; int row = e >> 6, kk = e & 63;
      int sw = kk ^ ((row & 7) << 3);
      *(u16x8*)&As[row * 64 + sw] = pa[j];
      *(u16x8*)&Bs[row * 64 + sw] = pb[j];
    }
    __syncthreads();
    if (k0 + 64 < K) {
#pragma unroll
      for (int j = 0; j < 4; ++j) {
        int e = (tid + j * 512) << 3; int row = e >> 6, kk = e & 63;
        pa[j] = *(const u16x8*)(A + (long)row * a_stride + k0 + 64 + kk);
        pb[j] = *(const u16x8*)(Bt + (long)(bcol0 + row) * b_stride + k0 + 64 + kk);
      }
    }
#pragma unroll
    for (int ks = 0; ks < 2; ++ks) {
      int kb = ks * 32 + lg * 8;
      s16x8 a[2];
#pragma unroll
      for (int m = 0; m < 2; ++m) {
        int row = wid * 32 + m * 16 + lr;
        a[m] = *(const s16x8*)&As[row * 64 + (kb ^ ((row & 7) << 3))];
      }
#pragma unroll
      for (int n = 0; n < 16; ++n) {
        int col = n * 16 + lr;
        s16x8 b = *(const s16x8*)&Bs[col * 64 + (kb ^ ((col & 7) << 3))];
        acc[0][n] = MFMA16(a[0], b, acc[0][n]);
        acc[1][n] = MFMA16(a[1], b, acc[1][n]);
      }
    }
    __syncthreads();
  }
}

// ---------------------------------------------------------------------------
// K23 (fused qkv+attention) per (window, head): 4096 blocks, 512 threads.
// Phase 1: GEMM qkvh = xb_window(256x256) @ Wqkv_head([96 cols][256 k])
//   using the proven 2-phase-prefetch pattern (As[256][64] 32KB,
//   Bs[96][64] 12KB, acc[2][6]).
// Epilogue: scatter acc -> LDS  q[256][32], k[256][32] (chunk-XOR
//   ((tok&3)<<3) layouts) and vt[32][256] (transposed + j-permuted,
//   byte-identical values to the old qkv global round-trip: f2bf(acc)).
// Phase 2: round-14 attention core verbatim, operands read from LDS.
// LDS: U 48KB (As/Bs union-> ql/kl/vt) + Pw 32KB = 80KB -> 2 blocks/CU.
// XCD grouping: the 8 heads of a window run consecutively on one XCD so
// the shared x-tile stays L2-hot.
// ---------------------------------------------------------------------------
__global__ __launch_bounds__(512) void k_qa(const unsigned short* __restrict__ xb,
    const unsigned short* __restrict__ wqkv_t, unsigned short* __restrict__ attn) {
  __shared__ __align__(16) unsigned short U[24576];    // 48 KB
  __shared__ __align__(16) unsigned short Pw[16384];   // 32 KB
  const int tid = threadIdx.x, wid = tid >> 6, lane = tid & 63, lr = lane & 15, lg = lane >> 4;
  const int orig = blockIdx.x;
  const int c = orig & 7, xx = orig >> 3;
  const int w = c * 64 + (xx >> 3), h = xx & 7;

  unsigned short* As = U;               // [256][64]
  unsigned short* Bs = U + 16384;       // [96][64]
  const unsigned short* A  = xb + (long)w * 65536;
  const unsigned short* Bt = wqkv_t + (long)(h * 96) * 256;

  const f32x4 Z = {0.f, 0.f, 0.f, 0.f};
  f32x4 acc[2][6];
#pragma unroll
  for (int m = 0; m < 2; ++m)
#pragma unroll
    for (int n = 0; n < 6; ++n) acc[m][n] = Z;

  // prologue loads (K-tile 0)
  u16x8 pa[4], pb[2];
#pragma unroll
  for (int j = 0; j < 4; ++j) {
    int e = (tid + j * 512) << 3; int row = e >> 6, kk = e & 63;
    pa[j] = *(const u16x8*)(A + (long)row * 256 + kk);
  }
  {
    int e = tid << 3; int c1 = e >> 6, k1 = e & 63;
    pb[0] = *(const u16x8*)(Bt + (long)c1 * 256 + k1);
    if (tid < 256) {
      int e2 = (tid + 512) << 3; int c2 = e2 >> 6, k2 = e2 & 63;
      pb[1] = *(const u16x8*)(Bt + (long)c2 * 256 + k2);
    }
  }

  for (int k0 = 0; k0 < 256; k0 += 64) {
#pragma unroll
    for (int j = 0; j < 4; ++j) {
      int e = (tid + j * 512) << 3; int row = e >> 6, kk = e & 63;
      *(u16x8*)&As[row * 64 + (kk ^ ((row & 7) << 3))] = pa[j];
    }
    {
      int e = tid << 3; int c1 = e >> 6, k1 = e & 63;
      *(u16x8*)&Bs[c1 * 64 + (k1 ^ ((c1 & 7) << 3))] = pb[0];
      if (tid < 256) {
        int e2 = (tid + 512) << 3; int c2 = e2 >> 6, k2 = e2 & 63;
        *(u16x8*)&Bs[c2 * 64 + (k2 ^ ((c2 & 7) << 3))] = pb[1];
      }
    }
    __syncthreads();
    if (k0 + 64 < 256) {
#pragma unroll
      for (int j = 0; j < 4; ++j) {
        int e = (tid + j * 512) << 3; int row = e >> 6, kk = e & 63;
        pa[j] = *(const u16x8*)(A + (long)row * 256 + k0 + 64 + kk);
      }
      int e = tid << 3; int c1 = e >> 6, k1 = e & 63;
      pb[0] = *(const u16x8*)(Bt + (long)c1 * 256 + k0 + 64 + k1);
      if (tid < 256) {
        int e2 = (tid + 512) << 3; int c2 = e2 >> 6, k2 = e2 & 63;
        pb[1] = *(const u16x8*)(Bt + (long)c2 * 256 + k0 + 64 + k2);
      }
    }
#pragma unroll
    for (int ks = 0; ks < 2; ++ks) {
      int kb = ks * 32 + lg * 8;
      s16x8 a[2];
#pragma unroll
      for (int m = 0; m < 2; ++m) {
        int row = wid * 32 + m * 16 + lr;
        a[m] = *(const s16x8*)&As[row * 64 + (kb ^ ((row & 7) << 3))];
      }
#pragma unroll
      for (int n = 0; n < 6; ++n) {
        int col = n * 16 + lr;
        s16x8 b = *(const s16x8*)&Bs[col * 64 + (kb ^ ((col & 7) << 3))];
        acc[0][n] = MFMA16(a[0], b, acc[0][n]);
        acc[1][n] = MFMA16(a[1], b, acc[1][n]);
      }
    }
    __syncthreads();   // also protects U before the epilogue overwrites it
  }

  // ---- epilogue: acc -> ql / kl / vt in LDS (f2bf = same values as before)
  unsigned short* ql = U;               // [256][32], chunk-XOR (tok&3)<<3
  unsigned short* kl = U + 8192;        // [256][32], chunk-XOR (j&3)<<3
  unsigned short* vt = U + 16384;       // [32][256], transposed + permuted
#pragma unroll
  for (int m = 0; m < 2; ++m)
#pragma unroll
    for (int r = 0; r < 4; ++r) {
      int tok = wid * 32 + m * 16 + lg * 4 + r;
      int p = (tok & 0xC0) | ((tok & 15) << 2) | ((tok >> 4) & 3);
#pragma unroll
      for (int n = 0; n < 2; ++n) {
        int d = n * 16 + lr;
        ql[tok * 32 + (d ^ ((tok & 3) << 3))] = f2bf(acc[m][n][r]);
      }
#pragma unroll
      for (int n = 2; n < 4; ++n) {
        int d = (n - 2) * 16 + lr;
        kl[tok * 32 + (d ^ ((tok & 3) << 3))] = f2bf(acc[m][n][r]);
      }
#pragma unroll
      for (int n = 4; n < 6; ++n) {
        int d = (n - 4) * 16 + lr;
        vt[d * 256 + (p ^ ((d & 7) << 3))] = f2bf(acc[m][n][r]);
      }
    }
  __syncthreads();   // ql/kl/vt staged

  // ---- attention core (round-14 proven, operands from LDS)
  s16x8 aq[2];
#pragma unroll
  for (int m = 0; m < 2; ++m) {
    int row = wid * 32 + m * 16 + lr;
    aq[m] = *(const s16x8*)&ql[row * 32 + ((lg * 8) ^ ((row & 3) << 3))];
  }

  f32x4 o[2][2];
  o[0][0] = Z; o[0][1] = Z; o[1][0] = Z; o[1][1] = Z;
  float fsum[2][4];
#pragma unroll
  for (int m = 0; m < 2; ++m)
#pragma unroll
    for (int r = 0; r < 4; ++r) fsum[m][r] = 0.f;

  unsigned short* P = &Pw[wid * 2048];

  const float SC = 0.17677669529663687f * 1.4426950408889634f;

#pragma unroll
  for (int qd = 0; qd < 4; ++qd) {
    f32x4 s[2][4];
#pragma unroll
    for (int m = 0; m < 2; ++m)
#pragma unroll
      for (int n4 = 0; n4 < 4; ++n4) s[m][n4] = Z;
#pragma unroll
    for (int n4 = 0; n4 < 4; ++n4) {
      int col = (qd * 4 + n4) * 16 + lr;
      s16x8 bfr = *(const s16x8*)&kl[col * 32 + ((lg * 8) ^ ((col & 3) << 3))];
      s[0][n4] = MFMA16(aq[0], bfr, s[0][n4]);
      s[1][n4] = MFMA16(aq[1], bfr, s[1][n4]);
    }
#pragma unroll
    for (int m = 0; m < 2; ++m)
#pragma unroll
      for (int r = 0; r < 4; ++r) {
        float p0, p1, p2, p3;
        asm("v_exp_f32 %0, %1" : "=v"(p0) : "v"(s[m][0][r] * SC));
        asm("v_exp_f32 %0, %1" : "=v"(p1) : "v"(s[m][1][r] * SC));
        asm("v_exp_f32 %0, %1" : "=v"(p2) : "v"(s[m][2][r] * SC));
        asm("v_exp_f32 %0, %1" : "=v"(p3) : "v"(s[m][3][r] * SC));
        fsum[m][r] += (p0 + p1) + (p2 + p3);
        unsigned lo, hi;
        asm("v_cvt_pk_bf16_f32 %0, %1, %2" : "=v"(lo) : "v"(p0), "v"(p1));
        asm("v_cvt_pk_bf16_f32 %0, %1, %2" : "=v"(hi) : "v"(p2), "v"(p3));
        int prow = m * 16 + lg * 4 + r;
        uint2 val; val.x = lo; val.y = hi;
        *(uint2*)&P[prow * 64 + ((lr * 4) ^ ((prow & 7) << 3))] = val;
      }
#pragma unroll
    for (int ks = 0; ks < 2; ++ks) {
      s16x8 pa2[2];
#pragma unroll
      for (int m = 0; m < 2; ++m) {
        int prow = m * 16 + lr;
        pa2[m] = *(const s16x8*)&P[prow * 64 + ((ks * 32 + lg * 8) ^ ((prow & 7) << 3))];
      }
#pragma unroll
      for (int nd = 0; nd < 2; ++nd) {
        int d = nd * 16 + lr;
        int jb = qd * 64 + ks * 32 + lg * 8;
        s16x8 vb = *(const s16x8*)&vt[d * 256 + (jb ^ ((d & 7) << 3))];
        o[0][nd] = MFMA16(pa2[0], vb, o[0][nd]);
        o[1][nd] = MFMA16(pa2[1], vb, o[1][nd]);
      }
    }
  }

  long obase = ((long)w * 256) * 256 + h * 32;
#pragma unroll
  for (int m = 0; m < 2; ++m)
#pragma unroll
    for (int r = 0; r < 4; ++r) {
      float rinv = 1.f / redsum16(fsum[m][r]);
      int tok = wid * 32 + m * 16 + lg * 4 + r;
#pragma unroll
      for (int nd = 0; nd < 2; ++nd) {
        int d = nd * 16 + lr;
        attn[obase + (long)tok * 256 + d] = f2bf(o[m][nd][r] * rinv);
      }
    }
}

// ---------------------------------------------------------------------------
// K4: out = attn @ W0 + x ; y = LN1(out)  (y bf16 to global)  [proven]
// ---------------------------------------------------------------------------
__global__ __launch_bounds__(512) void k_proj_ln1(
    const unsigned short* __restrict__ attn, const unsigned short* __restrict__ xb,
    const unsigned short* __restrict__ w0t, const float* __restrict__ g1,
    const float* __restrict__ be1, unsigned short* __restrict__ y) {
  __shared__ __align__(16) unsigned short As[256 * 64];
  __shared__ __align__(16) unsigned short Bs[256 * 64];
  int w = blockIdx.x;
  long row0 = (long)w * 256;
  f32x4 acc[2][16];
  gemm_block(attn + row0 * 256, 256, w0t, 0, 256, 256, As, Bs, acc);

  const int tid = threadIdx.x, wid = tid >> 6, lane = tid & 63, lr = lane & 15, lg = lane >> 4;
#pragma unroll
  for (int m = 0; m < 2; ++m)
#pragma unroll
    for (int r = 0; r < 4; ++r) {
      int row = wid * 32 + m * 16 + lg * 4 + r;
      long grow = row0 + row;
      float v[16]; float sum = 0.f;
#pragma unroll
      for (int n = 0; n < 16; ++n) {
        int col = n * 16 + lr;
        v[n] = acc[m][n][r] + bf2f(xb[grow * 256 + col]);
        sum += v[n];
      }
      sum = redsum16(sum);
      float mu = sum * (1.f / 256.f);
      float vs = 0.f;
#pragma unroll
      for (int n = 0; n < 16; ++n) { float dd = v[n] - mu; vs += dd * dd; }
      vs = redsum16(vs);
      float rstd = rsqrtf(vs * (1.f / 256.f) + 1e-5f);
#pragma unroll
      for (int n = 0; n < 16; ++n) {
        int col = n * 16 + lr;
        y[grow * 256 + col] = f2bf((v[n] - mu) * rstd * g1[col] + be1[col]);
      }
    }
}

// ---------------------------------------------------------------------------
// K5 (fused ff, v5 = round-14 BEST, verbatim): separate ps buffer, 80KB LDS,
// 3 barriers/slab, yfrag hoisted to registers.
// ---------------------------------------------------------------------------
__global__ __launch_bounds__(512) void k_ff(
    const unsigned short* __restrict__ y, const unsigned short* __restrict__ w1t,
    const float* __restrict__ b1, const unsigned short* __restrict__ w2tr,
    const float* __restrict__ b2, const float* __restrict__ g2,
    const float* __restrict__ be2, float* __restrict__ out) {
  __shared__ __align__(16) unsigned short w1s[64 * 256];   // 32 KB
  __shared__ __align__(16) unsigned short w2s[256 * 64];   // 32 KB
  __shared__ __align__(16) unsigned short ps[8 * 16 * 64]; // 16 KB
  const int tid = threadIdx.x, wid = tid >> 6, lane = tid & 63, lr = lane & 15, lg = lane >> 4;
  const long row0 = (long)blockIdx.x * 128;
  const f32x4 Z = {0.f, 0.f, 0.f, 0.f};

  const unsigned short* yrow = y + (row0 + wid * 16 + lr) * 256;

  s16x8 yfrag[8];
#pragma unroll
  for (int ks = 0; ks < 8; ++ks)
    yfrag[ks] = *(const s16x8*)(yrow + ks * 32 + lg * 8);

  f32x4 acc2[16];
#pragma unroll
  for (int n = 0; n < 16; ++n) acc2[n] = Z;
  unsigned short* P = ps + wid * 1024;   // [16][64] per wave

  u16x8 pw1[4], pw2[4];
#pragma unroll
  for (int j = 0; j < 4; ++j) {
    int e = (tid + j * 512) << 3;
    int c1 = e >> 8, k1 = e & 255;
    int c2 = e >> 6, k2 = e & 63;
    pw1[j] = *(const u16x8*)(w1t + (long)c1 * 256 + k1);
    pw2[j] = *(const u16x8*)(w2tr + (long)c2 * 512 + k2);
  }

  for (int s = 0; s < 8; ++s) {
#pragma unroll
    for (int j = 0; j < 4; ++j) {
      int e = (tid + j * 512) << 3;
      int c1 = e >> 8, k1 = e & 255;
      int c2 = e >> 6, k2 = e & 63;
      *(u16x8*)&w1s[c1 * 256 + (k1 ^ ((c1 & 7) << 3))] = pw1[j];
      *(u16x8*)&w2s[c2 * 64 + (k2 ^ ((c2 & 7) << 3))] = pw2[j];
    }
    __syncthreads();                                        // B1: staging visible
    if (s + 1 < 8) {
#pragma unroll
      for (int j = 0; j < 4; ++j) {
        int e = (tid + j * 512) << 3;
        int c1 = e >> 8, k1 = e & 255;
        int c2 = e >> 6, k2 = e & 63;
        pw1[j] = *(const u16x8*)(w1t + (long)((s + 1) * 64 + c1) * 256 + k1);
        pw2[j] = *(const u16x8*)(w2tr + (long)c2 * 512 + (s + 1) * 64 + k2);
      }
    }
    f32x4 sacc[4];
#pragma unroll
    for (int n4 = 0; n4 < 4; ++n4) sacc[n4] = Z;
#pragma unroll
    for (int ks = 0; ks < 8; ++ks) {
#pragma unroll
      for (int n4 = 0; n4 < 4; ++n4) {
        int col = n4 * 16 + lr;
        s16x8 b = *(const s16x8*)&w1s[col * 256 + ((ks * 32 + lg * 8) ^ ((col & 7) << 3))];
        sacc[n4] = MFMA16(yfrag[ks], b, sacc[n4]);
      }
    }
#pragma unroll
    for (int r = 0; r < 4; ++r) {
      int prow = lg * 4 + r;
      float p0 = fmaxf(sacc[0][r] + b1[s * 64 + lr], 0.f);
      float p1 = fmaxf(sacc[1][r] + b1[s * 64 + 16 + lr], 0.f);
      float p2 = fmaxf(sacc[2][r] + b1[s * 64 + 32 + lr], 0.f);
      float p3 = fmaxf(sacc[3][r] + b1[s * 64 + 48 + lr], 0.f);
      unsigned lo, hi;
      asm("v_cvt_pk_bf16_f32 %0, %1, %2" : "=v"(lo) : "v"(p0), "v"(p1));
      asm("v_cvt_pk_bf16_f32 %0, %1, %2" : "=v"(hi) : "v"(p2), "v"(p3));
      union { unsigned u[2]; s16x4 v; } pk;
      pk.u[0] = lo; pk.u[1] = hi;
      *(s16x4*)&P[prow * 64 + ((lr * 4) ^ ((prow & 7) << 3))] = pk.v;
    }
    __syncthreads();                                        // B2: P + w1s settled
#pragma unroll
    for (int ks2 = 0; ks2 < 2; ++ks2) {
      s16x8 pa2 = *(const s16x8*)&P[lr * 64 + ((ks2 * 32 + lg * 8) ^ ((lr & 7) << 3))];
#pragma unroll
      for (int n = 0; n < 16; ++n) {
        int col = n * 16 + lr;
        s16x8 b = *(const s16x8*)&w2s[col * 64 + ((ks2 * 32 + lg * 8) ^ ((col & 7) << 3))];
        acc2[n] = MFMA16(pa2, b, acc2[n]);
      }
    }
    __syncthreads();                                        // B3: reads done
  }

#pragma unroll
  for (int r = 0; r < 4; ++r) {
    int trow = wid * 16 + lg * 4 + r;
    long grow = row0 + trow;
    float v[16]; float sum = 0.f;
#pragma unroll
    for (int n = 0; n < 16; ++n) {
      int col = n * 16 + lr;
      v[n] = acc2[n][r] + b2[col] + bf2f(y[grow * 256 + col]);
      sum += v[n];
    }
    sum = redsum16(sum);
    float mu = sum * (1.f / 256.f);
    float vs = 0.f;
#pragma unroll
    for (int n = 0; n < 16; ++n) { float dd = v[n] - mu; vs += dd * dd; }
    vs = redsum16(vs);
    float rstd = rsqrtf(vs * (1.f / 256.f) + 1e-5f);
#pragma unroll
    for (int n = 0; n < 16; ++n) {
      int col = n * 16 + lr;
      out[grow * 256 + col] = (v[n] - mu) * rstd * g2[col] + be2[col];
    }
  }
}

// ---------------------------------------------------------------------------
// Launch. Workspace layout (bytes):
//   [0, 1MB)                weights bf16 (wqkv_t/w0t/w1t/w2tr)
//   [1MB, +67MB)            xb bf16
//   [1MB+67MB, +201MB)      y bf16 (region; qkv buffer no longer exists)
//   [1MB+67MB+201MB, +67MB) attn bf16
// ---------------------------------------------------------------------------
extern "C" void kernel_launch(void* const* d_in, const int* in_sizes, int n_in,
                              void* d_out, int out_size, void* d_ws, size_t ws_size,
                              hipStream_t stream) {
  (void)in_sizes; (void)n_in; (void)out_size; (void)ws_size;
  const float* x    = (const float*)d_in[0];
  const float* Wqkv = (const float*)d_in[1];
  const float* W0   = (const float*)d_in[2];
  const float* g1   = (const float*)d_in[3];
  const float* be1  = (const float*)d_in[4];
  const float* W1   = (const float*)d_in[5];
  const float* b1   = (const float*)d_in[6];
  const float* W2   = (const float*)d_in[7];
  const float* b2   = (const float*)d_in[8];
  const float* g2   = (const float*)d_in[9];
  const float* be2  = (const float*)d_in[10];
  float* out = (float*)d_out;
  char* ws = (char*)d_ws;

  unsigned short* wqkv_t = (unsigned short*)(ws);
  unsigned short* w0t    = (unsigned short*)(ws + 393216);
  unsigned short* w1t    = (unsigned short*)(ws + 524288);
  unsigned short* w2tr   = (unsigned short*)(ws + 786432);
  unsigned short* xb     = (unsigned short*)(ws + 1048576);
  char* regQ = ws + 1048576 + 67108864;
  unsigned short* y      = (unsigned short*)(regQ);
  unsigned short* attnb  = (unsigned short*)(regQ + 201326592);

  hipLaunchKernelGGL(k_cast, dim3(2048), dim3(256), 0, stream, x, xb);
  hipLaunchKernelGGL(k_prep, dim3(512), dim3(256), 0, stream,
                     Wqkv, W0, W1, W2, wqkv_t, w0t, w1t, w2tr);
  hipLaunchKernelGGL(k_qa, dim3(NWIN * 8), dim3(512), 0, stream, xb, wqkv_t, attnb);
  hipLaunchKernelGGL(k_proj_ln1, dim3(NWIN), dim3(512), 0, stream,
                     attnb, xb, w0t, g1, be1, y);
  hipLaunchKernelGGL(k_ff, dim3(NTOK / 128), dim3(512), 0, stream,
                     y, w1t, b1, w2tr, b2, g2, be2, out);
}

// Round 17
// 350.501 us; speedup vs baseline: 1.2740x; 1.0152x over previous
//
#include <hip/hip_runtime.h>
#include <hip/hip_bf16.h>
#include <stdint.h>

// Problem constants
// N=2, T=65536, DIM=256, HEADS=8, DH=32, NB=256 windows of TB=256 tokens, DFF=512
#define NTOK   131072      // N*T rows
#define NWIN   512         // N * NB

typedef __attribute__((ext_vector_type(4))) float f32x4;
typedef __attribute__((ext_vector_type(8))) short s16x8;
typedef __attribute__((ext_vector_type(4))) short s16x4;
typedef __attribute__((ext_vector_type(8))) unsigned short u16x8;

#define MFMA16(A,B,C) __builtin_amdgcn_mfma_f32_16x16x32_bf16(A,B,C,0,0,0)

__device__ __forceinline__ unsigned short f2bf(float f) {
  union { float f; unsigned u; } v; v.f = f;
  return (unsigned short)((v.u + 0x7fffu + ((v.u >> 16) & 1u)) >> 16);
}
__device__ __forceinline__ float bf2f(unsigned short u) {
  union { unsigned u; float f; } v; v.u = ((unsigned)u) << 16;
  return v.f;
}

__device__ __forceinline__ float redsum16(float v) {
  v += __shfl_xor(v, 1, 64);
  v += __shfl_xor(v, 2, 64);
  v += __shfl_xor(v, 4, 64);
  v += __shfl_xor(v, 8, 64);
  return v;
}

// ---------------------------------------------------------------------------
// K0: x fp32 -> xb bf16. Pure bandwidth.
// ---------------------------------------------------------------------------
__global__ __launch_bounds__(256) void k_cast(const float* __restrict__ x,
                                              unsigned short* __restrict__ xb) {
  const long total = (long)NTOK * 256 / 8;
  long stride = (long)gridDim.x * 256;
  for (long c = blockIdx.x * 256 + threadIdx.x; c < total; c += stride) {
    const f32x4* p = (const f32x4*)(x + c * 8);
    f32x4 v0 = p[0], v1 = p[1];
    u16x8 o;
    o[0] = f2bf(v0[0]); o[1] = f2bf(v0[1]); o[2] = f2bf(v0[2]); o[3] = f2bf(v0[3]);
    o[4] = f2bf(v1[0]); o[5] = f2bf(v1[1]); o[6] = f2bf(v1[2]); o[7] = f2bf(v1[3]);
    *(u16x8*)(xb + c * 8) = o;
  }
}

// ---------------------------------------------------------------------------
// Weight repack fp32->bf16, [outcol][k].
// Wqkv col regroup: src col = d*24 + s*8 + h -> dst col = h*96 + s*32 + d.
// W2 k-PERMUTED within each 64-block (round-8/9 proven): kp -> korig =
// (kp&~63) | ((kp&3)<<4) | ((kp>>2)&15)  — matches k_ff's P layout.
// ---------------------------------------------------------------------------
__global__ void k_prep(const float* __restrict__ Wqkv, const float* __restrict__ W0,
                       const float* __restrict__ W1,  const float* __restrict__ W2,
                       unsigned short* __restrict__ wqkv_t, unsigned short* __restrict__ w0t,
                       unsigned short* __restrict__ w1t,   unsigned short* __restrict__ w2tr) {
  int tid = blockIdx.x * 256 + threadIdx.x;
  int nthr = gridDim.x * 256;
  for (int i = tid; i < 768 * 256; i += nthr) {
    int col = i >> 8, k = i & 255;
    int h = col / 96, rem = col % 96;
    int s = rem >> 5, d = rem & 31;
    wqkv_t[i] = f2bf(Wqkv[k * 768 + d * 24 + s * 8 + h]);
  }
  for (int i = tid; i < 256 * 256; i += nthr) {
    int col = i >> 8, k = i & 255;
    w0t[i] = f2bf(W0[k * 256 + col]);
  }
  for (int i = tid; i < 512 * 256; i += nthr) {
    int col = i >> 8, k = i & 255;
    w1t[i] = f2bf(W1[k * 512 + col]);
  }
  for (int i = tid; i < 256 * 512; i += nthr) {
    int col = i >> 9, kp = i & 511;
    int korig = (kp & 0x1C0) | (((kp & 3) << 4) | ((kp >> 2) & 15));
    w2tr[i] = f2bf(W2[korig * 256 + col]);
  }
}

// ---------------------------------------------------------------------------
// Shared GEMM core (2-phase prefetch): C[256][256] = A[256][K] * Bt[col][k].
// (used by k_proj_ln1)
// ---------------------------------------------------------------------------
__device__ __forceinline__ void gemm_block(
    const unsigned short* __restrict__ A, int a_stride,
    const unsigned short* __restrict__ Bt, int bcol0, int b_stride, int K,
    unsigned short* As, unsigned short* Bs, f32x4 acc[2][16])
{
  const int tid = threadIdx.x;
  const int wid = tid >> 6, lane = tid & 63, lr = lane & 15, lg = lane >> 4;
  const f32x4 Z = {0.f, 0.f, 0.f, 0.f};
#pragma unroll
  for (int m = 0; m < 2; ++m)
#pragma unroll
    for (int n = 0; n < 16; ++n) acc[m][n] = Z;

  u16x8 pa[4], pb[4];
#pragma unroll
  for (int j = 0; j < 4; ++j) {
    int e = (tid + j * 512) << 3; int row = e >> 6, kk = e & 63;
    pa[j] = *(const u16x8*)(A + (long)row * a_stride + kk);
    pb[j] = *(const u16x8*)(Bt + (long)(bcol0 + row) * b_stride + kk);
  }

  for (int k0 = 0; k0 < K; k0 += 64) {
#pragma unroll
    for (int j = 0; j < 4; ++j) {
      int e = (tid + j * 512) << 3; int row = e >> 6, kk = e & 63;
      int sw = kk ^ ((row & 7) << 3);
      *(u16x8*)&As[row * 64 + sw] = pa[j];
      *(u16x8*)&Bs[row * 64 + sw] = pb[j];
    }
    __syncthreads();
    if (k0 + 64 < K) {
#pragma unroll
      for (int j = 0; j < 4; ++j) {
        int e = (tid + j * 512) << 3; int row = e >> 6, kk = e & 63;
        pa[j] = *(const u16x8*)(A + (long)row * a_stride + k0 + 64 + kk);
        pb[j] = *(const u16x8*)(Bt + (long)(bcol0 + row) * b_stride + k0 + 64 + kk);
      }
    }
#pragma unroll
    for (int ks = 0; ks < 2; ++ks) {
      int kb = ks * 32 + lg * 8;
      s16x8 a[2];
#pragma unroll
      for (int m = 0; m < 2; ++m) {
        int row = wid * 32 + m * 16 + lr;
        a[m] = *(const s16x8*)&As[row * 64 + (kb ^ ((row & 7) << 3))];
      }
#pragma unroll
      for (int n = 0; n < 16; ++n) {
        int col = n * 16 + lr;
        s16x8 b = *(const s16x8*)&Bs[col * 64 + (kb ^ ((col & 7) << 3))];
        acc[0][n] = MFMA16(a[0], b, acc[0][n]);
        acc[1][n] = MFMA16(a[1], b, acc[1][n]);
      }
    }
    __syncthreads();
  }
}

// ---------------------------------------------------------------------------
// K23 (fused qkv+attention) per (window, head): 4096 blocks, 512 threads.
// v2 changes vs round 16:
//  - LDS 80->64KB: Pw is 16KB (waves 0-3); waves 4-7 overlay P onto the
//    dead ql region (safe: aq registers are loaded from ql before any P
//    write, with a barrier between).  -> 2 blocks/CU.
//  - ql/kl XOR key changed (tok&3 -> (tok>>2)&3 == lg on write, lr>>2 on
//    read) killing the 8-way epilogue write conflict / 4-way read alias.
//  - softmax scale folded into the epilogue q write (plain C multiply on
//    acc, NOT an asm operand); exp takes raw s.
// ---------------------------------------------------------------------------
__global__ __launch_bounds__(512) void k_qa(const unsigned short* __restrict__ xb,
    const unsigned short* __restrict__ wqkv_t, unsigned short* __restrict__ attn) {
  __shared__ __align__(16) unsigned short U[24576];    // 48 KB
  __shared__ __align__(16) unsigned short Pw[8192];    // 16 KB (waves 0-3)
  const int tid = threadIdx.x, wid = tid >> 6, lane = tid & 63, lr = lane & 15, lg = lane >> 4;
  const int orig = blockIdx.x;
  const int c = orig & 7, xx = orig >> 3;
  const int w = c * 64 + (xx >> 3), h = xx & 7;

  unsigned short* As = U;               // [256][64]
  unsigned short* Bs = U + 16384;       // [96][64]
  const unsigned short* A  = xb + (long)w * 65536;
  const unsigned short* Bt = wqkv_t + (long)(h * 96) * 256;

  const f32x4 Z = {0.f, 0.f, 0.f, 0.f};
  f32x4 acc[2][6];
#pragma unroll
  for (int m = 0; m < 2; ++m)
#pragma unroll
    for (int n = 0; n < 6; ++n) acc[m][n] = Z;

  // prologue loads (K-tile 0)
  u16x8 pa[4], pb[2];
#pragma unroll
  for (int j = 0; j < 4; ++j) {
    int e = (tid + j * 512) << 3; int row = e >> 6, kk = e & 63;
    pa[j] = *(const u16x8*)(A + (long)row * 256 + kk);
  }
  {
    int e = tid << 3; int c1 = e >> 6, k1 = e & 63;
    pb[0] = *(const u16x8*)(Bt + (long)c1 * 256 + k1);
    if (tid < 256) {
      int e2 = (tid + 512) << 3; int c2 = e2 >> 6, k2 = e2 & 63;
      pb[1] = *(const u16x8*)(Bt + (long)c2 * 256 + k2);
    }
  }

  for (int k0 = 0; k0 < 256; k0 += 64) {
#pragma unroll
    for (int j = 0; j < 4; ++j) {
      int e = (tid + j * 512) << 3; int row = e >> 6, kk = e & 63;
      *(u16x8*)&As[row * 64 + (kk ^ ((row & 7) << 3))] = pa[j];
    }
    {
      int e = tid << 3; int c1 = e >> 6, k1 = e & 63;
      *(u16x8*)&Bs[c1 * 64 + (k1 ^ ((c1 & 7) << 3))] = pb[0];
      if (tid < 256) {
        int e2 = (tid + 512) << 3; int c2 = e2 >> 6, k2 = e2 & 63;
        *(u16x8*)&Bs[c2 * 64 + (k2 ^ ((c2 & 7) << 3))] = pb[1];
      }
    }
    __syncthreads();
    if (k0 + 64 < 256) {
#pragma unroll
      for (int j = 0; j < 4; ++j) {
        int e = (tid + j * 512) << 3; int row = e >> 6, kk = e & 63;
        pa[j] = *(const u16x8*)(A + (long)row * 256 + k0 + 64 + kk);
      }
      int e = tid << 3; int c1 = e >> 6, k1 = e & 63;
      pb[0] = *(const u16x8*)(Bt + (long)c1 * 256 + k0 + 64 + k1);
      if (tid < 256) {
        int e2 = (tid + 512) << 3; int c2 = e2 >> 6, k2 = e2 & 63;
        pb[1] = *(const u16x8*)(Bt + (long)c2 * 256 + k0 + 64 + k2);
      }
    }
#pragma unroll
    for (int ks = 0; ks < 2; ++ks) {
      int kb = ks * 32 + lg * 8;
      s16x8 a[2];
#pragma unroll
      for (int m = 0; m < 2; ++m) {
        int row = wid * 32 + m * 16 + lr;
        a[m] = *(const s16x8*)&As[row * 64 + (kb ^ ((row & 7) << 3))];
      }
#pragma unroll
      for (int n = 0; n < 6; ++n) {
        int col = n * 16 + lr;
        s16x8 b = *(const s16x8*)&Bs[col * 64 + (kb ^ ((col & 7) << 3))];
        acc[0][n] = MFMA16(a[0], b, acc[0][n]);
        acc[1][n] = MFMA16(a[1], b, acc[1][n]);
      }
    }
    __syncthreads();   // also protects U before the epilogue overwrites it
  }

  // softmax scale * log2(e) folded into q (v_exp_f32 computes 2^x)
  const float SC = 0.17677669529663687f * 1.4426950408889634f;

  // ---- epilogue: acc -> ql / kl / vt in LDS
  unsigned short* ql = U;               // [256][32], XOR key (tok>>2)&3 = lg
  unsigned short* kl = U + 8192;        // [256][32], same key
  unsigned short* vt = U + 16384;       // [32][256], transposed + permuted
#pragma unroll
  for (int m = 0; m < 2; ++m)
#pragma unroll
    for (int r = 0; r < 4; ++r) {
      int tok = wid * 32 + m * 16 + lg * 4 + r;
      int p = (tok & 0xC0) | ((tok & 15) << 2) | ((tok >> 4) & 3);
#pragma unroll
      for (int n = 0; n < 2; ++n) {
        int d = n * 16 + lr;
        ql[tok * 32 + (d ^ ((lg & 3) << 3))] = f2bf(acc[m][n][r] * SC);
      }
#pragma unroll
      for (int n = 2; n < 4; ++n) {
        int d = (n - 2) * 16 + lr;
        kl[tok * 32 + (d ^ ((lg & 3) << 3))] = f2bf(acc[m][n][r]);
      }
#pragma unroll
      for (int n = 4; n < 6; ++n) {
        int d = (n - 4) * 16 + lr;
        vt[d * 256 + (p ^ ((d & 7) << 3))] = f2bf(acc[m][n][r]);
      }
    }
  __syncthreads();   // ql/kl/vt staged

  // ---- load q fragments, then free ql for the P overlay (waves 4-7)
  s16x8 aq[2];
#pragma unroll
  for (int m = 0; m < 2; ++m) {
    int row = wid * 32 + m * 16 + lr;
    aq[m] = *(const s16x8*)&ql[row * 32 + ((lg * 8) ^ (((lr >> 2) & 3) << 3))];
  }
  __syncthreads();   // all aq loaded before any P write into the ql region

  f32x4 o[2][2];
  o[0][0] = Z; o[0][1] = Z; o[1][0] = Z; o[1][1] = Z;
  float fsum[2][4];
#pragma unroll
  for (int m = 0; m < 2; ++m)
#pragma unroll
    for (int r = 0; r < 4; ++r) fsum[m][r] = 0.f;

  unsigned short* P = (wid < 4) ? (Pw + wid * 2048) : (ql + (wid - 4) * 2048);

#pragma unroll
  for (int qd = 0; qd < 4; ++qd) {
    f32x4 s[2][4];
#pragma unroll
    for (int m = 0; m < 2; ++m)
#pragma unroll
      for (int n4 = 0; n4 < 4; ++n4) s[m][n4] = Z;
#pragma unroll
    for (int n4 = 0; n4 < 4; ++n4) {
      int col = (qd * 4 + n4) * 16 + lr;
      s16x8 bfr = *(const s16x8*)&kl[col * 32 + ((lg * 8) ^ (((lr >> 2) & 3) << 3))];
      s[0][n4] = MFMA16(aq[0], bfr, s[0][n4]);
      s[1][n4] = MFMA16(aq[1], bfr, s[1][n4]);
    }
#pragma unroll
    for (int m = 0; m < 2; ++m)
#pragma unroll
      for (int r = 0; r < 4; ++r) {
        float p0, p1, p2, p3;
        asm("v_exp_f32 %0, %1" : "=v"(p0) : "v"(s[m][0][r]));
        asm("v_exp_f32 %0, %1" : "=v"(p1) : "v"(s[m][1][r]));
        asm("v_exp_f32 %0, %1" : "=v"(p2) : "v"(s[m][2][r]));
        asm("v_exp_f32 %0, %1" : "=v"(p3) : "v"(s[m][3][r]));
        fsum[m][r] += (p0 + p1) + (p2 + p3);
        unsigned lo, hi;
        asm("v_cvt_pk_bf16_f32 %0, %1, %2" : "=v"(lo) : "v"(p0), "v"(p1));
        asm("v_cvt_pk_bf16_f32 %0, %1, %2" : "=v"(hi) : "v"(p2), "v"(p3));
        int prow = m * 16 + lg * 4 + r;
        uint2 val; val.x = lo; val.y = hi;
        *(uint2*)&P[prow * 64 + ((lr * 4) ^ ((prow & 7) << 3))] = val;
      }
#pragma unroll
    for (int ks = 0; ks < 2; ++ks) {
      s16x8 pa2[2];
#pragma unroll
      for (int m = 0; m < 2; ++m) {
        int prow = m * 16 + lr;
        pa2[m] = *(const s16x8*)&P[prow * 64 + ((ks * 32 + lg * 8) ^ ((prow & 7) << 3))];
      }
#pragma unroll
      for (int nd = 0; nd < 2; ++nd) {
        int d = nd * 16 + lr;
        int jb = qd * 64 + ks * 32 + lg * 8;
        s16x8 vb = *(const s16x8*)&vt[d * 256 + (jb ^ ((d & 7) << 3))];
        o[0][nd] = MFMA16(pa2[0], vb, o[0][nd]);
        o[1][nd] = MFMA16(pa2[1], vb, o[1][nd]);
      }
    }
  }

  long obase = ((long)w * 256) * 256 + h * 32;
#pragma unroll
  for (int m = 0; m < 2; ++m)
#pragma unroll
    for (int r = 0; r < 4; ++r) {
      float rinv = 1.f / redsum16(fsum[m][r]);
      int tok = wid * 32 + m * 16 + lg * 4 + r;
#pragma unroll
      for (int nd = 0; nd < 2; ++nd) {
        int d = nd * 16 + lr;
        attn[obase + (long)tok * 256 + d] = f2bf(o[m][nd][r] * rinv);
      }
    }
}

// ---------------------------------------------------------------------------
// K4: out = attn @ W0 + x ; y = LN1(out)  (y bf16 to global)  [proven]
// ---------------------------------------------------------------------------
__global__ __launch_bounds__(512) void k_proj_ln1(
    const unsigned short* __restrict__ attn, const unsigned short* __restrict__ xb,
    const unsigned short* __restrict__ w0t, const float* __restrict__ g1,
    const float* __restrict__ be1, unsigned short* __restrict__ y) {
  __shared__ __align__(16) unsigned short As[256 * 64];
  __shared__ __align__(16) unsigned short Bs[256 * 64];
  int w = blockIdx.x;
  long row0 = (long)w * 256;
  f32x4 acc[2][16];
  gemm_block(attn + row0 * 256, 256, w0t, 0, 256, 256, As, Bs, acc);

  const int tid = threadIdx.x, wid = tid >> 6, lane = tid & 63, lr = lane & 15, lg = lane >> 4;
#pragma unroll
  for (int m = 0; m < 2; ++m)
#pragma unroll
    for (int r = 0; r < 4; ++r) {
      int row = wid * 32 + m * 16 + lg * 4 + r;
      long grow = row0 + row;
      float v[16]; float sum = 0.f;
#pragma unroll
      for (int n = 0; n < 16; ++n) {
        int col = n * 16 + lr;
        v[n] = acc[m][n][r] + bf2f(xb[grow * 256 + col]);
        sum += v[n];
      }
      sum = redsum16(sum);
      float mu = sum * (1.f / 256.f);
      float vs = 0.f;
#pragma unroll
      for (int n = 0; n < 16; ++n) { float dd = v[n] - mu; vs += dd * dd; }
      vs = redsum16(vs);
      float rstd = rsqrtf(vs * (1.f / 256.f) + 1e-5f);
#pragma unroll
      for (int n = 0; n < 16; ++n) {
        int col = n * 16 + lr;
        y[grow * 256 + col] = f2bf((v[n] - mu) * rstd * g1[col] + be1[col]);
      }
    }
}

// ---------------------------------------------------------------------------
// K5 (fused ff, v5 = round-14 BEST, verbatim): separate ps buffer, 80KB LDS,
// 3 barriers/slab, yfrag hoisted to registers.
// ---------------------------------------------------------------------------
__global__ __launch_bounds__(512) void k_ff(
    const unsigned short* __restrict__ y, const unsigned short* __restrict__ w1t,
    const float* __restrict__ b1, const unsigned short* __restrict__ w2tr,
    const float* __restrict__ b2, const float* __restrict__ g2,
    const float* __restrict__ be2, float* __restrict__ out) {
  __shared__ __align__(16) unsigned short w1s[64 * 256];   // 32 KB
  __shared__ __align__(16) unsigned short w2s[256 * 64];   // 32 KB
  __shared__ __align__(16) unsigned short ps[8 * 16 * 64]; // 16 KB
  const int tid = threadIdx.x, wid = tid >> 6, lane = tid & 63, lr = lane & 15, lg = lane >> 4;
  const long row0 = (long)blockIdx.x * 128;
  const f32x4 Z = {0.f, 0.f, 0.f, 0.f};

  const unsigned short* yrow = y + (row0 + wid * 16 + lr) * 256;

  s16x8 yfrag[8];
#pragma unroll
  for (int ks = 0; ks < 8; ++ks)
    yfrag[ks] = *(const s16x8*)(yrow + ks * 32 + lg * 8);

  f32x4 acc2[16];
#pragma unroll
  for (int n = 0; n < 16; ++n) acc2[n] = Z;
  unsigned short* P = ps + wid * 1024;   // [16][64] per wave

  u16x8 pw1[4], pw2[4];
#pragma unroll
  for (int j = 0; j < 4; ++j) {
    int e = (tid + j * 512) << 3;
    int c1 = e >> 8, k1 = e & 255;
    int c2 = e >> 6, k2 = e & 63;
    pw1[j] = *(const u16x8*)(w1t + (long)c1 * 256 + k1);
    pw2[j] = *(const u16x8*)(w2tr + (long)c2 * 512 + k2);
  }

  for (int s = 0; s < 8; ++s) {
#pragma unroll
    for (int j = 0; j < 4; ++j) {
      int e = (tid + j * 512) << 3;
      int c1 = e >> 8, k1 = e & 255;
      int c2 = e >> 6, k2 = e & 63;
      *(u16x8*)&w1s[c1 * 256 + (k1 ^ ((c1 & 7) << 3))] = pw1[j];
      *(u16x8*)&w2s[c2 * 64 + (k2 ^ ((c2 & 7) << 3))] = pw2[j];
    }
    __syncthreads();                                        // B1: staging visible
    if (s + 1 < 8) {
#pragma unroll
      for (int j = 0; j < 4; ++j) {
        int e = (tid + j * 512) << 3;
        int c1 = e >> 8, k1 = e & 255;
        int c2 = e >> 6, k2 = e & 63;
        pw1[j] = *(const u16x8*)(w1t + (long)((s + 1) * 64 + c1) * 256 + k1);
        pw2[j] = *(const u16x8*)(w2tr + (long)c2 * 512 + (s + 1) * 64 + k2);
      }
    }
    f32x4 sacc[4];
#pragma unroll
    for (int n4 = 0; n4 < 4; ++n4) sacc[n4] = Z;
#pragma unroll
    for (int ks = 0; ks < 8; ++ks) {
#pragma unroll
      for (int n4 = 0; n4 < 4; ++n4) {
        int col = n4 * 16 + lr;
        s16x8 b = *(const s16x8*)&w1s[col * 256 + ((ks * 32 + lg * 8) ^ ((col & 7) << 3))];
        sacc[n4] = MFMA16(yfrag[ks], b, sacc[n4]);
      }
    }
#pragma unroll
    for (int r = 0; r < 4; ++r) {
      int prow = lg * 4 + r;
      float p0 = fmaxf(sacc[0][r] + b1[s * 64 + lr], 0.f);
      float p1 = fmaxf(sacc[1][r] + b1[s * 64 + 16 + lr], 0.f);
      float p2 = fmaxf(sacc[2][r] + b1[s * 64 + 32 + lr], 0.f);
      float p3 = fmaxf(sacc[3][r] + b1[s * 64 + 48 + lr], 0.f);
      unsigned lo, hi;
      asm("v_cvt_pk_bf16_f32 %0, %1, %2" : "=v"(lo) : "v"(p0), "v"(p1));
      asm("v_cvt_pk_bf16_f32 %0, %1, %2" : "=v"(hi) : "v"(p2), "v"(p3));
      union { unsigned u[2]; s16x4 v; } pk;
      pk.u[0] = lo; pk.u[1] = hi;
      *(s16x4*)&P[prow * 64 + ((lr * 4) ^ ((prow & 7) << 3))] = pk.v;
    }
    __syncthreads();                                        // B2: P + w1s settled
#pragma unroll
    for (int ks2 = 0; ks2 < 2; ++ks2) {
      s16x8 pa2 = *(const s16x8*)&P[lr * 64 + ((ks2 * 32 + lg * 8) ^ ((lr & 7) << 3))];
#pragma unroll
      for (int n = 0; n < 16; ++n) {
        int col = n * 16 + lr;
        s16x8 b = *(const s16x8*)&w2s[col * 64 + ((ks2 * 32 + lg * 8) ^ ((col & 7) << 3))];
        acc2[n] = MFMA16(pa2, b, acc2[n]);
      }
    }
    __syncthreads();                                        // B3: reads done
  }

#pragma unroll
  for (int r = 0; r < 4; ++r) {
    int trow = wid * 16 + lg * 4 + r;
    long grow = row0 + trow;
    float v[16]; float sum = 0.f;
#pragma unroll
    for (int n = 0; n < 16; ++n) {
      int col = n * 16 + lr;
      v[n] = acc2[n][r] + b2[col] + bf2f(y[grow * 256 + col]);
      sum += v[n];
    }
    sum = redsum16(sum);
    float mu = sum * (1.f / 256.f);
    float vs = 0.f;
#pragma unroll
    for (int n = 0; n < 16; ++n) { float dd = v[n] - mu; vs += dd * dd; }
    vs = redsum16(vs);
    float rstd = rsqrtf(vs * (1.f / 256.f) + 1e-5f);
#pragma unroll
    for (int n = 0; n < 16; ++n) {
      int col = n * 16 + lr;
      out[grow * 256 + col] = (v[n] - mu) * rstd * g2[col] + be2[col];
    }
  }
}

// ---------------------------------------------------------------------------
// Launch. Workspace layout (bytes):
//   [0, 1MB)                weights bf16 (wqkv_t/w0t/w1t/w2tr)
//   [1MB, +67MB)            xb bf16
//   [1MB+67MB, +201MB)      y bf16
//   [1MB+67MB+201MB, +67MB) attn bf16
// ---------------------------------------------------------------------------
extern "C" void kernel_launch(void* const* d_in, const int* in_sizes, int n_in,
                              void* d_out, int out_size, void* d_ws, size_t ws_size,
                              hipStream_t stream) {
  (void)in_sizes; (void)n_in; (void)out_size; (void)ws_size;
  const float* x    = (const float*)d_in[0];
  const float* Wqkv = (const float*)d_in[1];
  const float* W0   = (const float*)d_in[2];
  const float* g1   = (const float*)d_in[3];
  const float* be1  = (const float*)d_in[4];
  const float* W1   = (const float*)d_in[5];
  const float* b1   = (const float*)d_in[6];
  const float* W2   = (const float*)d_in[7];
  const float* b2   = (const float*)d_in[8];
  const float* g2   = (const float*)d_in[9];
  const float* be2  = (const float*)d_in[10];
  float* out = (float*)d_out;
  char* ws = (char*)d_ws;

  unsigned short* wqkv_t = (unsigned short*)(ws);
  unsigned short* w0t    = (unsigned short*)(ws + 393216);
  unsigned short* w1t    = (unsigned short*)(ws + 524288);
  unsigned short* w2tr   = (unsigned short*)(ws + 786432);
  unsigned short* xb     = (unsigned short*)(ws + 1048576);
  char* regQ = ws + 1048576 + 67108864;
  unsigned short* y      = (unsigned short*)(regQ);
  unsigned short* attnb  = (unsigned short*)(regQ + 201326592);

  hipLaunchKernelGGL(k_cast, dim3(2048), dim3(256), 0, stream, x, xb);
  hipLaunchKernelGGL(k_prep, dim3(512), dim3(256), 0, stream,
                     Wqkv, W0, W1, W2, wqkv_t, w0t, w1t, w2tr);
  hipLaunchKernelGGL(k_qa, dim3(NWIN * 8), dim3(512), 0, stream, xb, wqkv_t, attnb);
  hipLaunchKernelGGL(k_proj_ln1, dim3(NWIN), dim3(512), 0, stream,
                     attnb, xb, w0t, g1, be1, y);
  hipLaunchKernelGGL(k_ff, dim3(NTOK / 128), dim3(512), 0, stream,
                     y, w1t, b1, w2tr, b2, g2, be2, out);
}